// Round 13
// baseline (3999.472 us; speedup 1.0000x reference)
//
#include <hip/hip_runtime.h>
#include <math.h>

// Problem constants (fixed by the reference)
#define T_STEPS 512
#define BATCH   64
#define HID     512
#define NROW    2048          // 4*HID rows of concatenated W
#define HHIST   16777216ULL   // T*B*H floats (offset of i_hist in d_out)

typedef __attribute__((ext_vector_type(8))) short short8_t;   // 8 bf16
typedef __attribute__((ext_vector_type(4))) float float4_t;   // MFMA acc
typedef __attribute__((ext_vector_type(4))) unsigned uint4_t; // dwordx4

// ---------------------------------------------------------------------------
// helpers
// ---------------------------------------------------------------------------
__device__ __forceinline__ float sigf(float z) {
  z = fminf(fmaxf(z, -30.f), 30.f);
  return 1.f / (1.f + __expf(-z));
}
__device__ __forceinline__ float tanhf_(float v) {
  v = fminf(fmaxf(v, -15.f), 15.f);
  const float e = __expf(2.f * v);
  return (e - 1.f) / (e + 1.f);
}
__device__ __forceinline__ unsigned short bf16hi(float f) {
  unsigned u = __float_as_uint(f);
  return (unsigned short)((u + 0x7fffu + ((u >> 16) & 1u)) >> 16);  // RNE
}
__device__ __forceinline__ float bf16f(unsigned short h) {
  return __uint_as_float(((unsigned)h) << 16);
}
// pack f as (hi bf16 << 16) | (lo bf16): hi + lo ~ f to ~2^-17 rel.
__device__ __forceinline__ unsigned packh(float f) {
  unsigned short h = bf16hi(f);
  unsigned short l = bf16hi(f - bf16f(h));
  return (((unsigned)h) << 16) | (unsigned)l;
}

// Fast poll of one 64B row (8 tagged u64) via 4x global_load_dwordx4 sc0 —
// bypasses L1, served by this XCD's L2.
__device__ __forceinline__ bool poll_fast(const unsigned long long* hq, unsigned t,
                                          uint4_t& a, uint4_t& b,
                                          uint4_t& c, uint4_t& d) {
  asm volatile(
      "global_load_dwordx4 %0, %4, off sc0\n\t"
      "global_load_dwordx4 %1, %4, off offset:16 sc0\n\t"
      "global_load_dwordx4 %2, %4, off offset:32 sc0\n\t"
      "global_load_dwordx4 %3, %4, off offset:48 sc0\n\t"
      "s_waitcnt vmcnt(0)"
      : "=&v"(a), "=&v"(b), "=&v"(c), "=&v"(d)
      : "v"(hq)
      : "memory");
  return a[1] == t && a[3] == t && b[1] == t && b[3] == t &&
         c[1] == t && c[3] == t && d[1] == t && d[3] == t;
}

// Sentinel fast poll: 16B (two tagged u64) via one dwordx4 sc0.
__device__ __forceinline__ bool sent_fast(const unsigned long long* sq, unsigned t) {
  uint4_t s4;
  asm volatile(
      "global_load_dwordx4 %0, %1, off sc0\n\t"
      "s_waitcnt vmcnt(0)"
      : "=&v"(s4) : "v"(sq) : "memory");
  return s4[1] == t && s4[3] == t;
}

// ---------------------------------------------------------------------------
// Kernel A (unchanged): Zx[t][g][r][b8] = b[r] + sum_k Wx[r][k]*x[..]
// Layout [t][8 groups][2048 rows][8 b].
// ---------------------------------------------------------------------------
__global__ __launch_bounds__(256) void xgemm_kernel(
    const float* __restrict__ x,
    const float* __restrict__ Wf, const float* __restrict__ Wi,
    const float* __restrict__ Wo, const float* __restrict__ Wc,
    const float* __restrict__ bf, const float* __restrict__ bi,
    const float* __restrict__ bo, const float* __restrict__ bc,
    float* __restrict__ Zx)
{
  const int rtile = blockIdx.x;   // 0..15
  const int t     = blockIdx.y;   // 0..511
  const int g  = rtile >> 2;
  const int n0 = (rtile & 3) * 128;
  const float* Wg = (g == 0) ? Wf : (g == 1) ? Wi : (g == 2) ? Wo : Wc;
  const float* bg = (g == 0) ? bf : (g == 1) ? bi : (g == 2) ? bo : bc;

  __shared__ float Wt[32][132];   // [k][r] transposed, padded
  __shared__ float Xt[32][68];    // [k][b] transposed, padded

  const int tid = threadIdx.x;
  const int tr  = tid & 31;       // 4 r-rows each
  const int tb  = tid >> 5;       // 8 b-cols each (= batch group tb)

  float acc[4][8];
#pragma unroll
  for (int i = 0; i < 4; ++i)
#pragma unroll
    for (int j = 0; j < 8; ++j) acc[i][j] = 0.f;

  float biasv[4];
#pragma unroll
  for (int i = 0; i < 4; ++i) biasv[i] = bg[n0 + tr * 4 + i];

  const float* xt = x + (size_t)t * (BATCH * 512);

  for (int kc = 0; kc < 512; kc += 32) {
#pragma unroll
    for (int p = 0; p < 4; ++p) {
      const int r  = p * 32 + (tid >> 3);
      const int kk = (tid & 7) * 4;
      float4 v = *(const float4*)&Wg[(size_t)(n0 + r) * 1024 + 512 + kc + kk];
      Wt[kk + 0][r] = v.x; Wt[kk + 1][r] = v.y;
      Wt[kk + 2][r] = v.z; Wt[kk + 3][r] = v.w;
    }
    {
      const int b  = tid >> 2;
      const int kk = (tid & 3) * 8;
      float4 v0 = *(const float4*)&xt[b * 512 + kc + kk];
      float4 v1 = *(const float4*)&xt[b * 512 + kc + kk + 4];
      Xt[kk + 0][b] = v0.x; Xt[kk + 1][b] = v0.y;
      Xt[kk + 2][b] = v0.z; Xt[kk + 3][b] = v0.w;
      Xt[kk + 4][b] = v1.x; Xt[kk + 5][b] = v1.y;
      Xt[kk + 6][b] = v1.z; Xt[kk + 7][b] = v1.w;
    }
    __syncthreads();
#pragma unroll
    for (int kk = 0; kk < 32; ++kk) {
      float4 wv = *(const float4*)&Wt[kk][tr * 4];
      float4 x0 = *(const float4*)&Xt[kk][tb * 8];
      float4 x1 = *(const float4*)&Xt[kk][tb * 8 + 4];
      const float wa[4] = {wv.x, wv.y, wv.z, wv.w};
      const float xa[8] = {x0.x, x0.y, x0.z, x0.w, x1.x, x1.y, x1.z, x1.w};
#pragma unroll
      for (int i = 0; i < 4; ++i)
#pragma unroll
        for (int j = 0; j < 8; ++j)
          acc[i][j] = fmaf(wa[i], xa[j], acc[i][j]);
    }
    __syncthreads();
  }

  const int rg = g * 512 + n0 + tr * 4;
#pragma unroll
  for (int ir = 0; ir < 4; ++ir) {
    const float bv = biasv[ir];
    float4 o0 = make_float4(acc[ir][0] + bv, acc[ir][1] + bv,
                            acc[ir][2] + bv, acc[ir][3] + bv);
    float4 o1 = make_float4(acc[ir][4] + bv, acc[ir][5] + bv,
                            acc[ir][6] + bv, acc[ir][7] + bv);
    // [t][group = tb][row][8 b]
    float* dst = Zx + (((size_t)t * 8 + tb) * NROW + rg + ir) * 8;
    *(float4*)dst       = o0;
    *(float4*)(dst + 4) = o1;
  }
}

// ---------------------------------------------------------------------------
// Kernel B (fast): r12 structure (XCD-discovered groups, MFMA, in-wave
// epilogue, adaptive L2/MALL polling) + SENTINEL PRE-WAIT to kill the L2
// poll storm:
//  - producer wave publishes its 8 h-words, then (program order) ONE tagged
//    sentinel u64 per wave (dual plain+sc1, like the data).
//  - consumer lane l's row (units 8l..8l+8) corresponds exactly to producer
//    wave sentinels 2l, 2l+1 -> poll ONE 16B line until epoch==t, then do
//    the tag-verified 64B row read (expected 1 iteration).
//  - tags on the data words remain ground truth (store visibility order is
//    not guaranteed), so the sentinel is purely a traffic optimization;
//    all fallback paths (agent/MALL) preserved -> correctness unchanged.
// ---------------------------------------------------------------------------
__global__ __launch_bounds__(512, 2) void lstm_rec_fast(
    const float* __restrict__ mask,
    const float* __restrict__ Wf, const float* __restrict__ Wi,
    const float* __restrict__ Wo, const float* __restrict__ Wc,
    const float* __restrict__ Zx,
    unsigned long long* __restrict__ hP,   // [2][8 g][8 b][512 k] tagged
    unsigned* __restrict__ xb,             // [0..7] cnt, [15] barrier
    unsigned long long* __restrict__ hS,   // [2][8 g][128] wave sentinels
    float* __restrict__ out)
{
  __shared__ __align__(16) short hip_[2][8 * 512];  // hi planes [buf][b][k]
  __shared__ __align__(16) short lop_[2][8 * 512];  // lo planes
  __shared__ unsigned s_role;

  const int tid  = threadIdx.x;

  // ---- phase 0: XCD discovery + role assignment (once) ----
  if (tid == 0) {
    unsigned xcd;
    asm volatile("s_getreg_b32 %0, hwreg(20, 0, 32)" : "=s"(xcd));
    xcd &= 7u;
    const unsigned slot = __hip_atomic_fetch_add(&xb[xcd], 1u, __ATOMIC_RELAXED,
                                                 __HIP_MEMORY_SCOPE_AGENT);
    __builtin_amdgcn_fence(__ATOMIC_RELEASE, "agent");
    __hip_atomic_fetch_add(&xb[15], 1u, __ATOMIC_RELAXED,
                           __HIP_MEMORY_SCOPE_AGENT);
    const unsigned nwg = gridDim.x;
    while (__hip_atomic_load(&xb[15], __ATOMIC_RELAXED,
                             __HIP_MEMORY_SCOPE_AGENT) < nwg)
      __builtin_amdgcn_s_sleep(2);
    __builtin_amdgcn_fence(__ATOMIC_ACQUIRE, "agent");
    unsigned pfx = 0;
    for (unsigned xx = 0; xx < xcd; ++xx)
      pfx += __hip_atomic_load(&xb[xx], __ATOMIC_RELAXED,
                               __HIP_MEMORY_SCOPE_AGENT);
    s_role = pfx + slot;
  }
  __syncthreads();
  const unsigned role = s_role;
  const int g  = (int)(role >> 4);          // batch group (XCD-grouped)
  const int m  = (int)(role & 15u);         // member in group
  const int n0 = m * 32;                    // first unit of this wg

  const int wv   = tid >> 6;          // wave 0..7
  const int lane = tid & 63;
  const int kq   = lane >> 4;         // k-block / D unit-quadrant
  const int l15  = lane & 15;

  // ---- A fragments: row m = l15 = u_local*4 + gate; k = it*32 + kq*8 + j
  const int gateA = l15 & 3;
  const int unitA = n0 + wv * 4 + (l15 >> 2);
  const float* WmA =
      (gateA == 0) ? Wf : (gateA == 1) ? Wi : (gateA == 2) ? Wo : Wc;
  const float* WrowA = WmA + (size_t)unitA * 1024;   // h-part cols 0..511
  short8_t Ahi[16], Alo[16];
#pragma unroll
  for (int it = 0; it < 16; ++it) {
    const int base = it * 32 + kq * 8;
#pragma unroll
    for (int j = 0; j < 8; ++j) {
      const float f = WrowA[base + j];
      const unsigned short h = bf16hi(f);
      Ahi[it][j] = (short)h;
      Alo[it][j] = (short)bf16hi(f - bf16f(h));
    }
  }

  // epilogue identity: lane holds gates of (unitD, bD); active if l15 < 8
  const int unitD = n0 + wv * 4 + kq;
  const int bD    = l15;
  const bool act  = (l15 < 8);
  float c_r = 0.f, h_r = 0.f;

  // staging identity: thread owns (b_s, kr..kr+7) -> ONE producer wg
  const int b_s = tid >> 6;            // 0..7
  const int kr  = (tid & 63) * 8;      // k start
  const int bcol = l15 & 7;            // dot-side B row (lanes 8-15 duplicate)

  bool fastok = true;                  // per-(consumer,producer) adaptive

  // ---- prologue: Zx/mask for t=0 (in flight during first poll)
  float zxc[4] = {0.f, 0.f, 0.f, 0.f};
  float mvc = 0.f;
  if (act) {
    mvc = mask[g * 8 + bD];
#pragma unroll
    for (int r = 0; r < 4; ++r)
      zxc[r] = Zx[(((size_t)0 * 8 + g) * NROW + r * 512 + unitD) * 8 + bD];
  }

  for (int t = 0; t < T_STEPS; ++t) {
    // ---- sentinel pre-wait: lane polls its 2 wave-sentinels (one 16B line)
    {
      const unsigned long long* sq =
          hS + (((size_t)(t & 1) * 8 + g) << 7) + 2 * (tid & 63);
      bool sgot = false;
      if (fastok) {
        for (int it2 = 0; it2 < 96 && !sgot; ++it2)
          sgot = sent_fast(sq, (unsigned)t);
        if (!sgot) fastok = false;   // producer not L2-visible: MALL from now
      }
      if (!sgot) {
        while (true) {
          unsigned long long s0 = __hip_atomic_load(sq, __ATOMIC_RELAXED,
                                                    __HIP_MEMORY_SCOPE_AGENT);
          unsigned long long s1 = __hip_atomic_load(sq + 1, __ATOMIC_RELAXED,
                                                    __HIP_MEMORY_SCOPE_AGENT);
          if ((unsigned)(s0 >> 32) == (unsigned)t &&
              (unsigned)(s1 >> 32) == (unsigned)t)
            break;
          __builtin_amdgcn_s_sleep(1);
        }
      }
    }

    // ---- tag-verified row read (expected ~1 iteration after sentinel)
    {
      const unsigned long long* hq =
          hP + (((size_t)(t & 1) * 8 + g) * 8 + b_s) * 512 + kr;
      unsigned p8[8];
      bool got = false;
      if (fastok) {
        uint4_t a, b, c, d;
        for (int it2 = 0; it2 < 32 && !got; ++it2)
          got = poll_fast(hq, (unsigned)t, a, b, c, d);
        if (got) {
          p8[0] = a[0]; p8[1] = a[2]; p8[2] = b[0]; p8[3] = b[2];
          p8[4] = c[0]; p8[5] = c[2]; p8[6] = d[0]; p8[7] = d[2];
        } else {
          fastok = false;
        }
      }
      if (!got) {
        unsigned long long q[8];
        while (true) {
#pragma unroll
          for (int j = 0; j < 8; ++j)
            q[j] = __hip_atomic_load(hq + j, __ATOMIC_RELAXED,
                                     __HIP_MEMORY_SCOPE_AGENT);
          bool ok = true;
#pragma unroll
          for (int j = 0; j < 8; ++j)
            ok &= ((unsigned)(q[j] >> 32) == (unsigned)t);
          if (ok) break;
          __builtin_amdgcn_s_sleep(1);
        }
#pragma unroll
        for (int j = 0; j < 8; ++j) p8[j] = (unsigned)q[j];
      }
      short8_t H, L;
#pragma unroll
      for (int j = 0; j < 8; ++j) {
        H[j] = (short)(p8[j] >> 16);
        L[j] = (short)(p8[j] & 0xffffu);
      }
      const int sOff = b_s * 1024 + ((kr * 2) ^ ((b_s & 7) << 4));
      *(short8_t*)((char*)hip_[t & 1] + sOff) = H;
      *(short8_t*)((char*)lop_[t & 1] + sOff) = L;
    }

    // ---- prefetch t+1's Zx/mask (consumed next epilogue; latency hidden)
    float zxn[4] = {0.f, 0.f, 0.f, 0.f};
    float mvn = 0.f;
    if (act && t + 1 < T_STEPS) {
      mvn = mask[(t + 1) * 64 + g * 8 + bD];
#pragma unroll
      for (int r = 0; r < 4; ++r)
        zxn[r] = Zx[(((size_t)(t + 1) * 8 + g) * NROW + r * 512 + unitD) * 8 + bD];
    }

    __syncthreads();   // the ONLY per-step barrier: planes ready

    // ---- MFMA: 16 rows x 16 cols x K=512, 3-pass split-bf16
    float4_t c0 = {0.f, 0.f, 0.f, 0.f};
    float4_t c1 = {0.f, 0.f, 0.f, 0.f};
    float4_t c2 = {0.f, 0.f, 0.f, 0.f};
    {
      const char* hib = (const char*)hip_[t & 1] + bcol * 1024;
      const char* lob = (const char*)lop_[t & 1] + bcol * 1024;
      const int xr = bcol << 4;
#pragma unroll
      for (int it = 0; it < 16; ++it) {
        const int o = it * 64 + kq * 16;
        const short8_t bh = *(const short8_t*)(hib + (o ^ xr));
        const short8_t bl = *(const short8_t*)(lob + (o ^ xr));
        c0 = __builtin_amdgcn_mfma_f32_16x16x32_bf16(Ahi[it], bh, c0, 0, 0, 0);
        c1 = __builtin_amdgcn_mfma_f32_16x16x32_bf16(Ahi[it], bl, c1, 0, 0, 0);
        c2 = __builtin_amdgcn_mfma_f32_16x16x32_bf16(Alo[it], bh, c2, 0, 0, 0);
      }
    }

    // ---- per-lane epilogue: r = gate (rows kq*4+r), no cross-lane traffic
    if (act) {
      float z[4];
#pragma unroll
      for (int r = 0; r < 4; ++r) z[r] = c0[r] + c1[r] + c2[r] + zxc[r];
      const float f  = sigf(z[0]);
      const float ig = sigf(z[1]);
      const float o  = sigf(z[2]);
      const float ct = tanhf_(z[3]);
      float cn = f * c_r + ig * ct;
      cn = mvc * cn + (1.f - mvc) * c_r;
      c_r = cn;
      float hn = o * tanhf_(cn);
      hn = mvc * hn + (1.f - mvc) * h_r;
      h_r = hn;
      // dual publish (same address): plain -> local XCD L2 (fast path);
      // sc1 agent -> MALL (robust path, keeps fallback always-correct)
      const size_t hidx =
          (((size_t)((t + 1) & 1) * 8 + g) * 8 + bD) * 512 + unitD;
      const unsigned long long pk =
          (((unsigned long long)(unsigned)(t + 1)) << 32) |
          (unsigned long long)packh(hn);
      *(volatile unsigned long long*)(hP + hidx) = pk;
      __hip_atomic_store(hP + hidx, pk, __ATOMIC_RELAXED,
                         __HIP_MEMORY_SCOPE_AGENT);
      // per-wave sentinel: issued AFTER the h stores in program order.
      // (Visibility order isn't guaranteed -> data tags remain the truth.)
      if (lane == 0) {
        unsigned long long* sp =
            hS + (((size_t)((t + 1) & 1) * 8 + g) << 7) + (m * 8 + wv);
        const unsigned long long sv =
            ((unsigned long long)(unsigned)(t + 1)) << 32;
        *(volatile unsigned long long*)sp = sv;
        __hip_atomic_store(sp, sv, __ATOMIC_RELAXED,
                           __HIP_MEMORY_SCOPE_AGENT);
      }
      // history outputs: plain stores (ack at L2, no fences anywhere)
      const size_t ob = ((size_t)t * 64 + g * 8 + bD) * 512 + unitD;
      out[ob] = hn;
      out[HHIST + ob] = ig;
    }

    // rotate Zx double-buffer
#pragma unroll
    for (int r = 0; r < 4; ++r) zxc[r] = zxn[r];
    mvc = mvn;
  }
}

// ---------------------------------------------------------------------------
// Fallback (ws too small): round-3 inline-x cooperative version, verbatim.
// ---------------------------------------------------------------------------
__device__ __forceinline__ void grid_barrier(unsigned* cnt, int w, int tid, int round) {
  __syncthreads();
  if (tid == 0) {
    __builtin_amdgcn_fence(__ATOMIC_RELEASE, "agent");
    unsigned* gc = cnt + 16 + ((w >> 4) << 5);
    unsigned prev = __hip_atomic_fetch_add(gc, 1u, __ATOMIC_RELAXED,
                                           __HIP_MEMORY_SCOPE_AGENT);
    if ((prev & 15u) == 15u)
      __hip_atomic_fetch_add(cnt, 1u, __ATOMIC_RELAXED,
                             __HIP_MEMORY_SCOPE_AGENT);
    const unsigned target = (unsigned)(round + 1) * 16u;
    while (__hip_atomic_load(cnt, __ATOMIC_RELAXED,
                             __HIP_MEMORY_SCOPE_AGENT) < target)
      __builtin_amdgcn_s_sleep(2);
    __builtin_amdgcn_fence(__ATOMIC_ACQUIRE, "agent");
  }
  __syncthreads();
}

__global__ __launch_bounds__(512) void lstm_rec_inline(
    const float* __restrict__ x,  const float* __restrict__ mask,
    const float* __restrict__ Wf, const float* __restrict__ Wi,
    const float* __restrict__ Wo, const float* __restrict__ Wc,
    const float* __restrict__ bf, const float* __restrict__ bi,
    const float* __restrict__ bo, const float* __restrict__ bc,
    float* __restrict__ hT, unsigned* __restrict__ cnt,
    float* __restrict__ out)
{
  constexpr int WC = 1024;
  __shared__ float Wlds[8 * WC];
  __shared__ float zpart[8 * 8 * 64];

  const int tid = threadIdx.x;
  const int w   = blockIdx.x;
  const int kq  = tid >> 6;
  const int b   = tid & 63;
  const int n0  = ((w & 7) << 6) + ((w >> 3) << 1);

#pragma unroll
  for (int i = 0; i < WC / 256; ++i) {
    const int idx4 = tid + (i << 9);
    const int rr   = idx4 / (WC / 4);
    const int col  = (idx4 % (WC / 4)) * 4;
    const int g = rr >> 1, u = rr & 1;
    const float* Wrow =
        ((g == 0) ? Wf : (g == 1) ? Wi : (g == 2) ? Wo : Wc) +
        (size_t)(n0 + u) * 1024;
    *(float4*)&Wlds[rr * WC + col] = *(const float4*)&Wrow[col];
  }

  float biasv[4] = {0.f, 0.f, 0.f, 0.f};
  float c_r = 0.f, h_r = 0.f;
  if (tid < 128) {
    const int u = tid >> 6;
    biasv[0] = bf[n0 + u]; biasv[1] = bi[n0 + u];
    biasv[2] = bo[n0 + u]; biasv[3] = bc[n0 + u];
  }
  __syncthreads();

  for (int t = 0; t < T_STEPS; ++t) {
    float zpre[4] = {0.f, 0.f, 0.f, 0.f};
    float mval = 0.f;
    if (tid < 128) {
      const int bb = tid & 63;
      mval = mask[t * 64 + bb];
#pragma unroll
      for (int g = 0; g < 4; ++g) zpre[g] = biasv[g];
    }

    float acc[8];
#pragma unroll
    for (int rr = 0; rr < 8; ++rr) acc[rr] = 0.f;

    {
      const float* hcur = hT + ((t & 1) << 15);
      const int k0 = kq << 6;
#pragma unroll
      for (int k4 = 0; k4 < 16; ++k4) {
        const int k = k0 + (k4 << 2);
        const float h0 = hcur[(k + 0) * 64 + b];
        const float h1 = hcur[(k + 1) * 64 + b];
        const float h2 = hcur[(k + 2) * 64 + b];
        const float h3 = hcur[(k + 3) * 64 + b];
#pragma unroll
        for (int rr = 0; rr < 8; ++rr) {
          float4 wv = *(const float4*)&Wlds[rr * WC + k];
          acc[rr] = fmaf(h0, wv.x, acc[rr]);
          acc[rr] = fmaf(h1, wv.y, acc[rr]);
          acc[rr] = fmaf(h2, wv.z, acc[rr]);
          acc[rr] = fmaf(h3, wv.w, acc[rr]);
        }
      }
    }
    {
      const float* xt = x + (size_t)t * (64 * 512) + b * 512;
      const int k0 = kq << 6;
#pragma unroll
      for (int k4 = 0; k4 < 16; ++k4) {
        const int k = k0 + (k4 << 2);
        float4 xv = *(const float4*)&xt[k];
#pragma unroll
        for (int rr = 0; rr < 8; ++rr) {
          float4 wv = *(const float4*)&Wlds[rr * WC + 512 + k];
          acc[rr] = fmaf(xv.x, wv.x, acc[rr]);
          acc[rr] = fmaf(xv.y, wv.y, acc[rr]);
          acc[rr] = fmaf(xv.z, wv.z, acc[rr]);
          acc[rr] = fmaf(xv.w, wv.w, acc[rr]);
        }
      }
    }

#pragma unroll
    for (int rr = 0; rr < 8; ++rr)
      zpart[((kq << 3) + rr) * 64 + b] = acc[rr];
    __syncthreads();

    if (tid < 128) {
      const int u = tid >> 6, bb = tid & 63;
      float z[4];
#pragma unroll
      for (int g = 0; g < 4; ++g) {
        const int rr = g * 2 + u;
        float s = zpre[g];
#pragma unroll
        for (int q = 0; q < 8; ++q) s += zpart[((q << 3) + rr) * 64 + bb];
        z[g] = s;
      }
      const float f  = sigf(z[0]);
      const float ig = sigf(z[1]);
      const float o  = sigf(z[2]);
      const float ct = tanhf_(z[3]);
      float cn = f * c_r + ig * ct;
      cn = mval * cn + (1.f - mval) * c_r;
      c_r = cn;
      float hn = o * tanhf_(cn);
      hn = mval * hn + (1.f - mval) * h_r;
      h_r = hn;
      const int n = n0 + u;
      hT[(((t + 1) & 1) << 15) + n * 64 + bb] = hn;
      out[((size_t)t * 64 + bb) * 512 + n]         = hn;
      out[HHIST + ((size_t)t * 64 + bb) * 512 + n] = ig;
    }

    if (t != T_STEPS - 1) grid_barrier(cnt, w, tid, t);
  }
}

// ---------------------------------------------------------------------------
// launch
// ---------------------------------------------------------------------------
extern "C" void kernel_launch(void* const* d_in, const int* in_sizes, int n_in,
                              void* d_out, int out_size, void* d_ws, size_t ws_size,
                              hipStream_t stream) {
  (void)in_sizes; (void)n_in; (void)out_size;
  // setup_inputs order: x, mask, Wf, bf, Wi, bi, Wc, bc, Wo, bo
  const float* x    = (const float*)d_in[0];
  const float* mask = (const float*)d_in[1];
  const float* Wf   = (const float*)d_in[2];
  const float* bf   = (const float*)d_in[3];
  const float* Wi   = (const float*)d_in[4];
  const float* bi   = (const float*)d_in[5];
  const float* Wc   = (const float*)d_in[6];
  const float* bc   = (const float*)d_in[7];
  const float* Wo   = (const float*)d_in[8];
  const float* bo   = (const float*)d_in[9];
  float* out = (float*)d_out;

  const size_t zx_bytes = (size_t)T_STEPS * NROW * 64 * 4;      // 256 MiB
  const size_t hp_bytes = (size_t)2 * 8 * 8 * 512 * 8;          // 512 KiB
  const size_t xb_bytes = 4096;
  const size_t hs_bytes = (size_t)2 * 8 * 128 * 8;              // 16 KiB
  const bool fast = ws_size >= zx_bytes + hp_bytes + xb_bytes + hs_bytes;

  if (fast) {
    float* Zx = (float*)d_ws;
    unsigned long long* hP = (unsigned long long*)((char*)d_ws + zx_bytes);
    unsigned* xb = (unsigned*)((char*)hP + hp_bytes);
    unsigned long long* hS = (unsigned long long*)((char*)xb + xb_bytes);
    // zero tagged buffer (epoch 0 = t=0 initial h) + counters + sentinels
    hipMemsetAsync(hP, 0, hp_bytes + xb_bytes + hs_bytes, stream);
    hipLaunchKernelGGL(xgemm_kernel, dim3(16, 512), dim3(256), 0, stream,
                       x, Wf, Wi, Wo, Wc, bf, bi, bo, bc, Zx);
    void* kargs[] = { (void*)&mask, (void*)&Wf, (void*)&Wi, (void*)&Wo,
                      (void*)&Wc, (void*)&Zx, (void*)&hP, (void*)&xb,
                      (void*)&hS, (void*)&out };
    hipLaunchCooperativeKernel(reinterpret_cast<void*>(&lstm_rec_fast),
                               dim3(128), dim3(512), kargs, 0, stream);
  } else {
    float* hT = (float*)d_ws;
    const size_t h_bytes = 2 * 64 * 512 * 4;                    // 256 KiB
    unsigned* cnt = (unsigned*)((char*)hT + h_bytes);
    hipMemsetAsync(hT, 0, h_bytes + 4096, stream);
    void* kargs[] = { (void*)&x, (void*)&mask, (void*)&Wf, (void*)&Wi,
                      (void*)&Wo, (void*)&Wc, (void*)&bf, (void*)&bi,
                      (void*)&bo, (void*)&bc, (void*)&hT, (void*)&cnt,
                      (void*)&out };
    hipLaunchCooperativeKernel(reinterpret_cast<void*>(&lstm_rec_inline),
                               dim3(256), dim3(512), kargs, 0, stream);
  }
}

// Round 14
// 3466.884 us; speedup vs baseline: 1.1536x; 1.1536x over previous
//
#include <hip/hip_runtime.h>
#include <math.h>

// Problem constants (fixed by the reference)
#define T_STEPS 512
#define BATCH   64
#define HID     512
#define NROW    2048          // 4*HID rows of concatenated W
#define HHIST   16777216ULL   // T*B*H floats (offset of i_hist in d_out)

typedef __attribute__((ext_vector_type(8))) short short8_t;   // 8 bf16
typedef __attribute__((ext_vector_type(4))) float float4_t;   // MFMA acc
typedef __attribute__((ext_vector_type(4))) unsigned uint4_t; // dwordx4

// ---------------------------------------------------------------------------
// helpers
// ---------------------------------------------------------------------------
__device__ __forceinline__ float sigf(float z) {
  z = fminf(fmaxf(z, -30.f), 30.f);
  return 1.f / (1.f + __expf(-z));
}
__device__ __forceinline__ float tanhf_(float v) {
  v = fminf(fmaxf(v, -15.f), 15.f);
  const float e = __expf(2.f * v);
  return (e - 1.f) / (e + 1.f);
}
__device__ __forceinline__ unsigned short bf16hi(float f) {
  unsigned u = __float_as_uint(f);
  return (unsigned short)((u + 0x7fffu + ((u >> 16) & 1u)) >> 16);  // RNE
}
__device__ __forceinline__ float bf16f(unsigned short h) {
  return __uint_as_float(((unsigned)h) << 16);
}
// pack f as (hi bf16 << 16) | (lo bf16): hi + lo ~ f to ~2^-17 rel.
__device__ __forceinline__ unsigned packh(float f) {
  unsigned short h = bf16hi(f);
  unsigned short l = bf16hi(f - bf16f(h));
  return (((unsigned)h) << 16) | (unsigned)l;
}

// Fast poll of one 64B row (8 tagged u64) via 4x global_load_dwordx4 sc0 —
// bypasses L1, served by this XCD's L2. With nt streaming elsewhere, the
// hP slab stays L2-resident and this is a genuine L2 hit.
__device__ __forceinline__ bool poll_fast(const unsigned long long* hq, unsigned t,
                                          uint4_t& a, uint4_t& b,
                                          uint4_t& c, uint4_t& d) {
  asm volatile(
      "global_load_dwordx4 %0, %4, off sc0\n\t"
      "global_load_dwordx4 %1, %4, off offset:16 sc0\n\t"
      "global_load_dwordx4 %2, %4, off offset:32 sc0\n\t"
      "global_load_dwordx4 %3, %4, off offset:48 sc0\n\t"
      "s_waitcnt vmcnt(0)"
      : "=&v"(a), "=&v"(b), "=&v"(c), "=&v"(d)
      : "v"(hq)
      : "memory");
  return a[1] == t && a[3] == t && b[1] == t && b[3] == t &&
         c[1] == t && c[3] == t && d[1] == t && d[3] == t;
}

// ---------------------------------------------------------------------------
// Kernel A (unchanged): Zx[t][g][r][b8] = b[r] + sum_k Wx[r][k]*x[..]
// Layout [t][8 groups][2048 rows][8 b].
// ---------------------------------------------------------------------------
__global__ __launch_bounds__(256) void xgemm_kernel(
    const float* __restrict__ x,
    const float* __restrict__ Wf, const float* __restrict__ Wi,
    const float* __restrict__ Wo, const float* __restrict__ Wc,
    const float* __restrict__ bf, const float* __restrict__ bi,
    const float* __restrict__ bo, const float* __restrict__ bc,
    float* __restrict__ Zx)
{
  const int rtile = blockIdx.x;   // 0..15
  const int t     = blockIdx.y;   // 0..511
  const int g  = rtile >> 2;
  const int n0 = (rtile & 3) * 128;
  const float* Wg = (g == 0) ? Wf : (g == 1) ? Wi : (g == 2) ? Wo : Wc;
  const float* bg = (g == 0) ? bf : (g == 1) ? bi : (g == 2) ? bo : bc;

  __shared__ float Wt[32][132];   // [k][r] transposed, padded
  __shared__ float Xt[32][68];    // [k][b] transposed, padded

  const int tid = threadIdx.x;
  const int tr  = tid & 31;       // 4 r-rows each
  const int tb  = tid >> 5;       // 8 b-cols each (= batch group tb)

  float acc[4][8];
#pragma unroll
  for (int i = 0; i < 4; ++i)
#pragma unroll
    for (int j = 0; j < 8; ++j) acc[i][j] = 0.f;

  float biasv[4];
#pragma unroll
  for (int i = 0; i < 4; ++i) biasv[i] = bg[n0 + tr * 4 + i];

  const float* xt = x + (size_t)t * (BATCH * 512);

  for (int kc = 0; kc < 512; kc += 32) {
#pragma unroll
    for (int p = 0; p < 4; ++p) {
      const int r  = p * 32 + (tid >> 3);
      const int kk = (tid & 7) * 4;
      float4 v = *(const float4*)&Wg[(size_t)(n0 + r) * 1024 + 512 + kc + kk];
      Wt[kk + 0][r] = v.x; Wt[kk + 1][r] = v.y;
      Wt[kk + 2][r] = v.z; Wt[kk + 3][r] = v.w;
    }
    {
      const int b  = tid >> 2;
      const int kk = (tid & 3) * 8;
      float4 v0 = *(const float4*)&xt[b * 512 + kc + kk];
      float4 v1 = *(const float4*)&xt[b * 512 + kc + kk + 4];
      Xt[kk + 0][b] = v0.x; Xt[kk + 1][b] = v0.y;
      Xt[kk + 2][b] = v0.z; Xt[kk + 3][b] = v0.w;
      Xt[kk + 4][b] = v1.x; Xt[kk + 5][b] = v1.y;
      Xt[kk + 6][b] = v1.z; Xt[kk + 7][b] = v1.w;
    }
    __syncthreads();
#pragma unroll
    for (int kk = 0; kk < 32; ++kk) {
      float4 wv = *(const float4*)&Wt[kk][tr * 4];
      float4 x0 = *(const float4*)&Xt[kk][tb * 8];
      float4 x1 = *(const float4*)&Xt[kk][tb * 8 + 4];
      const float wa[4] = {wv.x, wv.y, wv.z, wv.w};
      const float xa[8] = {x0.x, x0.y, x0.z, x0.w, x1.x, x1.y, x1.z, x1.w};
#pragma unroll
      for (int i = 0; i < 4; ++i)
#pragma unroll
        for (int j = 0; j < 8; ++j)
          acc[i][j] = fmaf(wa[i], xa[j], acc[i][j]);
    }
    __syncthreads();
  }

  const int rg = g * 512 + n0 + tr * 4;
#pragma unroll
  for (int ir = 0; ir < 4; ++ir) {
    const float bv = biasv[ir];
    float4 o0 = make_float4(acc[ir][0] + bv, acc[ir][1] + bv,
                            acc[ir][2] + bv, acc[ir][3] + bv);
    float4 o1 = make_float4(acc[ir][4] + bv, acc[ir][5] + bv,
                            acc[ir][6] + bv, acc[ir][7] + bv);
    // [t][group = tb][row][8 b]
    float* dst = Zx + (((size_t)t * 8 + tb) * NROW + rg + ir) * 8;
    *(float4*)dst       = o0;
    *(float4*)(dst + 4) = o1;
  }
}

// ---------------------------------------------------------------------------
// Kernel B (fast): r12 structure (XCD-discovered groups, MFMA, in-wave
// epilogue, adaptive L2/MALL polling, Zx register double-buffer), with the
// STREAMS FENCED OUT OF L2:
//  - Zx/mask prefetches use nontemporal loads (nt: no L2 fill/eviction)
//  - out history stores use nontemporal stores (no dirty L2 lines)
// so the 64KB/group hP slab stays L2-resident and every fast poll is a
// genuine ~L2-hit. No sentinel (r13: it added a serial hop, -19%).
// Correctness identical to r12: epoch tags are ground truth; plain+sc1
// dual publish; adaptive permanent fallback to agent/MALL polling.
// ---------------------------------------------------------------------------
__global__ __launch_bounds__(512, 2) void lstm_rec_fast(
    const float* __restrict__ mask,
    const float* __restrict__ Wf, const float* __restrict__ Wi,
    const float* __restrict__ Wo, const float* __restrict__ Wc,
    const float* __restrict__ Zx,
    unsigned long long* __restrict__ hP,   // [2][8 g][8 b][512 k] tagged
    unsigned* __restrict__ xb,             // [0..7] cnt, [15] barrier
    float* __restrict__ out)
{
  __shared__ __align__(16) short hip_[2][8 * 512];  // hi planes [buf][b][k]
  __shared__ __align__(16) short lop_[2][8 * 512];  // lo planes
  __shared__ unsigned s_role;

  const int tid  = threadIdx.x;

  // ---- phase 0: XCD discovery + role assignment (once) ----
  if (tid == 0) {
    unsigned xcd;
    asm volatile("s_getreg_b32 %0, hwreg(20, 0, 32)" : "=s"(xcd));
    xcd &= 7u;
    const unsigned slot = __hip_atomic_fetch_add(&xb[xcd], 1u, __ATOMIC_RELAXED,
                                                 __HIP_MEMORY_SCOPE_AGENT);
    __builtin_amdgcn_fence(__ATOMIC_RELEASE, "agent");
    __hip_atomic_fetch_add(&xb[15], 1u, __ATOMIC_RELAXED,
                           __HIP_MEMORY_SCOPE_AGENT);
    const unsigned nwg = gridDim.x;
    while (__hip_atomic_load(&xb[15], __ATOMIC_RELAXED,
                             __HIP_MEMORY_SCOPE_AGENT) < nwg)
      __builtin_amdgcn_s_sleep(2);
    __builtin_amdgcn_fence(__ATOMIC_ACQUIRE, "agent");
    unsigned pfx = 0;
    for (unsigned xx = 0; xx < xcd; ++xx)
      pfx += __hip_atomic_load(&xb[xx], __ATOMIC_RELAXED,
                               __HIP_MEMORY_SCOPE_AGENT);
    s_role = pfx + slot;
  }
  __syncthreads();
  const unsigned role = s_role;
  const int g  = (int)(role >> 4);          // batch group (XCD-grouped)
  const int n0 = (int)(role & 15u) * 32;    // first unit of this wg

  const int wv   = tid >> 6;          // wave 0..7
  const int lane = tid & 63;
  const int kq   = lane >> 4;         // k-block / D unit-quadrant
  const int l15  = lane & 15;

  // ---- A fragments: row m = l15 = u_local*4 + gate; k = it*32 + kq*8 + j
  const int gateA = l15 & 3;
  const int unitA = n0 + wv * 4 + (l15 >> 2);
  const float* WmA =
      (gateA == 0) ? Wf : (gateA == 1) ? Wi : (gateA == 2) ? Wo : Wc;
  const float* WrowA = WmA + (size_t)unitA * 1024;   // h-part cols 0..511
  short8_t Ahi[16], Alo[16];
#pragma unroll
  for (int it = 0; it < 16; ++it) {
    const int base = it * 32 + kq * 8;
#pragma unroll
    for (int j = 0; j < 8; ++j) {
      const float f = WrowA[base + j];
      const unsigned short h = bf16hi(f);
      Ahi[it][j] = (short)h;
      Alo[it][j] = (short)bf16hi(f - bf16f(h));
    }
  }

  // epilogue identity: lane holds gates of (unitD, bD); active if l15 < 8
  const int unitD = n0 + wv * 4 + kq;
  const int bD    = l15;
  const bool act  = (l15 < 8);
  float c_r = 0.f, h_r = 0.f;

  // staging identity: thread owns (b_s, kr..kr+7) -> exactly ONE producer wg
  const int b_s = tid >> 6;            // 0..7
  const int kr  = (tid & 63) * 8;      // k start
  const int bcol = l15 & 7;            // dot-side B row (lanes 8-15 duplicate)

  bool fastok = true;                  // per-(consumer,producer) adaptive

  // ---- prologue: Zx/mask for t=0 (nt loads; in flight during first poll)
  float zxc[4] = {0.f, 0.f, 0.f, 0.f};
  float mvc = 0.f;
  if (act) {
    mvc = __builtin_nontemporal_load(&mask[g * 8 + bD]);
#pragma unroll
    for (int r = 0; r < 4; ++r)
      zxc[r] = __builtin_nontemporal_load(
          &Zx[(((size_t)0 * 8 + g) * NROW + r * 512 + unitD) * 8 + bD]);
  }

  for (int t = 0; t < T_STEPS; ++t) {
    // ---- poll own 8 tagged pairs: adaptive L2-fast / MALL-robust
    {
      const unsigned long long* hq =
          hP + (((size_t)(t & 1) * 8 + g) * 8 + b_s) * 512 + kr;
      unsigned p8[8];
      bool got = false;
      if (fastok) {
        uint4_t a, b, c, d;
        for (int it2 = 0; it2 < 64 && !got; ++it2)
          got = poll_fast(hq, (unsigned)t, a, b, c, d);
        if (got) {
          p8[0] = a[0]; p8[1] = a[2]; p8[2] = b[0]; p8[3] = b[2];
          p8[4] = c[0]; p8[5] = c[2]; p8[6] = d[0]; p8[7] = d[2];
        } else {
          fastok = false;   // producer not L2-visible: use MALL from now on
        }
      }
      if (!got) {
        unsigned long long q[8];
        while (true) {
#pragma unroll
          for (int j = 0; j < 8; ++j)
            q[j] = __hip_atomic_load(hq + j, __ATOMIC_RELAXED,
                                     __HIP_MEMORY_SCOPE_AGENT);
          bool ok = true;
#pragma unroll
          for (int j = 0; j < 8; ++j)
            ok &= ((unsigned)(q[j] >> 32) == (unsigned)t);
          if (ok) break;
          __builtin_amdgcn_s_sleep(1);
        }
#pragma unroll
        for (int j = 0; j < 8; ++j) p8[j] = (unsigned)q[j];
      }
      short8_t H, L;
#pragma unroll
      for (int j = 0; j < 8; ++j) {
        H[j] = (short)(p8[j] >> 16);
        L[j] = (short)(p8[j] & 0xffffu);
      }
      const int sOff = b_s * 1024 + ((kr * 2) ^ ((b_s & 7) << 4));
      *(short8_t*)((char*)hip_[t & 1] + sOff) = H;
      *(short8_t*)((char*)lop_[t & 1] + sOff) = L;
    }

    // ---- prefetch t+1's Zx/mask (nt: no L2 pollution; consumed at the
    // NEXT step's epilogue, so HBM latency hides under barrier+MFMA)
    float zxn[4] = {0.f, 0.f, 0.f, 0.f};
    float mvn = 0.f;
    if (act && t + 1 < T_STEPS) {
      mvn = __builtin_nontemporal_load(&mask[(t + 1) * 64 + g * 8 + bD]);
#pragma unroll
      for (int r = 0; r < 4; ++r)
        zxn[r] = __builtin_nontemporal_load(
            &Zx[(((size_t)(t + 1) * 8 + g) * NROW + r * 512 + unitD) * 8 + bD]);
    }

    __syncthreads();   // the ONLY per-step barrier: planes ready

    // ---- MFMA: 16 rows x 16 cols x K=512, 3-pass split-bf16
    float4_t c0 = {0.f, 0.f, 0.f, 0.f};
    float4_t c1 = {0.f, 0.f, 0.f, 0.f};
    float4_t c2 = {0.f, 0.f, 0.f, 0.f};
    {
      const char* hib = (const char*)hip_[t & 1] + bcol * 1024;
      const char* lob = (const char*)lop_[t & 1] + bcol * 1024;
      const int xr = bcol << 4;
#pragma unroll
      for (int it = 0; it < 16; ++it) {
        const int o = it * 64 + kq * 16;
        const short8_t bh = *(const short8_t*)(hib + (o ^ xr));
        const short8_t bl = *(const short8_t*)(lob + (o ^ xr));
        c0 = __builtin_amdgcn_mfma_f32_16x16x32_bf16(Ahi[it], bh, c0, 0, 0, 0);
        c1 = __builtin_amdgcn_mfma_f32_16x16x32_bf16(Ahi[it], bl, c1, 0, 0, 0);
        c2 = __builtin_amdgcn_mfma_f32_16x16x32_bf16(Alo[it], bh, c2, 0, 0, 0);
      }
    }

    // ---- per-lane epilogue: r = gate (rows kq*4+r), no cross-lane traffic
    if (act) {
      float z[4];
#pragma unroll
      for (int r = 0; r < 4; ++r) z[r] = c0[r] + c1[r] + c2[r] + zxc[r];
      const float f  = sigf(z[0]);
      const float ig = sigf(z[1]);
      const float o  = sigf(z[2]);
      const float ct = tanhf_(z[3]);
      float cn = f * c_r + ig * ct;
      cn = mvc * cn + (1.f - mvc) * c_r;
      c_r = cn;
      float hn = o * tanhf_(cn);
      hn = mvc * hn + (1.f - mvc) * h_r;
      h_r = hn;
      // dual publish (same address): plain -> local XCD L2 (fast path);
      // sc1 agent -> MALL (robust path, keeps fallback always-correct)
      const size_t hidx =
          (((size_t)((t + 1) & 1) * 8 + g) * 8 + bD) * 512 + unitD;
      const unsigned long long pk =
          (((unsigned long long)(unsigned)(t + 1)) << 32) |
          (unsigned long long)packh(hn);
      *(volatile unsigned long long*)(hP + hidx) = pk;
      __hip_atomic_store(hP + hidx, pk, __ATOMIC_RELAXED,
                         __HIP_MEMORY_SCOPE_AGENT);
      // history outputs: nontemporal (no dirty L2 lines, no writeback storm)
      const size_t ob = ((size_t)t * 64 + g * 8 + bD) * 512 + unitD;
      __builtin_nontemporal_store(hn, &out[ob]);
      __builtin_nontemporal_store(ig, &out[HHIST + ob]);
    }

    // rotate Zx double-buffer
#pragma unroll
    for (int r = 0; r < 4; ++r) zxc[r] = zxn[r];
    mvc = mvn;
  }
}

// ---------------------------------------------------------------------------
// Fallback (ws too small): round-3 inline-x cooperative version, verbatim.
// ---------------------------------------------------------------------------
__device__ __forceinline__ void grid_barrier(unsigned* cnt, int w, int tid, int round) {
  __syncthreads();
  if (tid == 0) {
    __builtin_amdgcn_fence(__ATOMIC_RELEASE, "agent");
    unsigned* gc = cnt + 16 + ((w >> 4) << 5);
    unsigned prev = __hip_atomic_fetch_add(gc, 1u, __ATOMIC_RELAXED,
                                           __HIP_MEMORY_SCOPE_AGENT);
    if ((prev & 15u) == 15u)
      __hip_atomic_fetch_add(cnt, 1u, __ATOMIC_RELAXED,
                             __HIP_MEMORY_SCOPE_AGENT);
    const unsigned target = (unsigned)(round + 1) * 16u;
    while (__hip_atomic_load(cnt, __ATOMIC_RELAXED,
                             __HIP_MEMORY_SCOPE_AGENT) < target)
      __builtin_amdgcn_s_sleep(2);
    __builtin_amdgcn_fence(__ATOMIC_ACQUIRE, "agent");
  }
  __syncthreads();
}

__global__ __launch_bounds__(512) void lstm_rec_inline(
    const float* __restrict__ x,  const float* __restrict__ mask,
    const float* __restrict__ Wf, const float* __restrict__ Wi,
    const float* __restrict__ Wo, const float* __restrict__ Wc,
    const float* __restrict__ bf, const float* __restrict__ bi,
    const float* __restrict__ bo, const float* __restrict__ bc,
    float* __restrict__ hT, unsigned* __restrict__ cnt,
    float* __restrict__ out)
{
  constexpr int WC = 1024;
  __shared__ float Wlds[8 * WC];
  __shared__ float zpart[8 * 8 * 64];

  const int tid = threadIdx.x;
  const int w   = blockIdx.x;
  const int kq  = tid >> 6;
  const int b   = tid & 63;
  const int n0  = ((w & 7) << 6) + ((w >> 3) << 1);

#pragma unroll
  for (int i = 0; i < WC / 256; ++i) {
    const int idx4 = tid + (i << 9);
    const int rr   = idx4 / (WC / 4);
    const int col  = (idx4 % (WC / 4)) * 4;
    const int g = rr >> 1, u = rr & 1;
    const float* Wrow =
        ((g == 0) ? Wf : (g == 1) ? Wi : (g == 2) ? Wo : Wc) +
        (size_t)(n0 + u) * 1024;
    *(float4*)&Wlds[rr * WC + col] = *(const float4*)&Wrow[col];
  }

  float biasv[4] = {0.f, 0.f, 0.f, 0.f};
  float c_r = 0.f, h_r = 0.f;
  if (tid < 128) {
    const int u = tid >> 6;
    biasv[0] = bf[n0 + u]; biasv[1] = bi[n0 + u];
    biasv[2] = bo[n0 + u]; biasv[3] = bc[n0 + u];
  }
  __syncthreads();

  for (int t = 0; t < T_STEPS; ++t) {
    float zpre[4] = {0.f, 0.f, 0.f, 0.f};
    float mval = 0.f;
    if (tid < 128) {
      const int bb = tid & 63;
      mval = mask[t * 64 + bb];
#pragma unroll
      for (int g = 0; g < 4; ++g) zpre[g] = biasv[g];
    }

    float acc[8];
#pragma unroll
    for (int rr = 0; rr < 8; ++rr) acc[rr] = 0.f;

    {
      const float* hcur = hT + ((t & 1) << 15);
      const int k0 = kq << 6;
#pragma unroll
      for (int k4 = 0; k4 < 16; ++k4) {
        const int k = k0 + (k4 << 2);
        const float h0 = hcur[(k + 0) * 64 + b];
        const float h1 = hcur[(k + 1) * 64 + b];
        const float h2 = hcur[(k + 2) * 64 + b];
        const float h3 = hcur[(k + 3) * 64 + b];
#pragma unroll
        for (int rr = 0; rr < 8; ++rr) {
          float4 wv = *(const float4*)&Wlds[rr * WC + k];
          acc[rr] = fmaf(h0, wv.x, acc[rr]);
          acc[rr] = fmaf(h1, wv.y, acc[rr]);
          acc[rr] = fmaf(h2, wv.z, acc[rr]);
          acc[rr] = fmaf(h3, wv.w, acc[rr]);
        }
      }
    }
    {
      const float* xt = x + (size_t)t * (64 * 512) + b * 512;
      const int k0 = kq << 6;
#pragma unroll
      for (int k4 = 0; k4 < 16; ++k4) {
        const int k = k0 + (k4 << 2);
        float4 xv = *(const float4*)&xt[k];
#pragma unroll
        for (int rr = 0; rr < 8; ++rr) {
          float4 wv = *(const float4*)&Wlds[rr * WC + 512 + k];
          acc[rr] = fmaf(xv.x, wv.x, acc[rr]);
          acc[rr] = fmaf(xv.y, wv.y, acc[rr]);
          acc[rr] = fmaf(xv.z, wv.z, acc[rr]);
          acc[rr] = fmaf(xv.w, wv.w, acc[rr]);
        }
      }
    }

#pragma unroll
    for (int rr = 0; rr < 8; ++rr)
      zpart[((kq << 3) + rr) * 64 + b] = acc[rr];
    __syncthreads();

    if (tid < 128) {
      const int u = tid >> 6, bb = tid & 63;
      float z[4];
#pragma unroll
      for (int g = 0; g < 4; ++g) {
        const int rr = g * 2 + u;
        float s = zpre[g];
#pragma unroll
        for (int q = 0; q < 8; ++q) s += zpart[((q << 3) + rr) * 64 + bb];
        z[g] = s;
      }
      const float f  = sigf(z[0]);
      const float ig = sigf(z[1]);
      const float o  = sigf(z[2]);
      const float ct = tanhf_(z[3]);
      float cn = f * c_r + ig * ct;
      cn = mval * cn + (1.f - mval) * c_r;
      c_r = cn;
      float hn = o * tanhf_(cn);
      hn = mval * hn + (1.f - mval) * h_r;
      h_r = hn;
      const int n = n0 + u;
      hT[(((t + 1) & 1) << 15) + n * 64 + bb] = hn;
      out[((size_t)t * 64 + bb) * 512 + n]         = hn;
      out[HHIST + ((size_t)t * 64 + bb) * 512 + n] = ig;
    }

    if (t != T_STEPS - 1) grid_barrier(cnt, w, tid, t);
  }
}

// ---------------------------------------------------------------------------
// launch
// ---------------------------------------------------------------------------
extern "C" void kernel_launch(void* const* d_in, const int* in_sizes, int n_in,
                              void* d_out, int out_size, void* d_ws, size_t ws_size,
                              hipStream_t stream) {
  (void)in_sizes; (void)n_in; (void)out_size;
  // setup_inputs order: x, mask, Wf, bf, Wi, bi, Wc, bc, Wo, bo
  const float* x    = (const float*)d_in[0];
  const float* mask = (const float*)d_in[1];
  const float* Wf   = (const float*)d_in[2];
  const float* bf   = (const float*)d_in[3];
  const float* Wi   = (const float*)d_in[4];
  const float* bi   = (const float*)d_in[5];
  const float* Wc   = (const float*)d_in[6];
  const float* bc   = (const float*)d_in[7];
  const float* Wo   = (const float*)d_in[8];
  const float* bo   = (const float*)d_in[9];
  float* out = (float*)d_out;

  const size_t zx_bytes = (size_t)T_STEPS * NROW * 64 * 4;      // 256 MiB
  const size_t hp_bytes = (size_t)2 * 8 * 8 * 512 * 8;          // 512 KiB
  const bool fast = ws_size >= zx_bytes + hp_bytes + 4096;

  if (fast) {
    float* Zx = (float*)d_ws;
    unsigned long long* hP = (unsigned long long*)((char*)d_ws + zx_bytes);
    unsigned* xb = (unsigned*)((char*)hP + hp_bytes);
    // zero tagged buffer (epoch 0 = t=0 initial h) + discovery counters
    hipMemsetAsync(hP, 0, hp_bytes + 4096, stream);
    hipLaunchKernelGGL(xgemm_kernel, dim3(16, 512), dim3(256), 0, stream,
                       x, Wf, Wi, Wo, Wc, bf, bi, bo, bc, Zx);
    void* kargs[] = { (void*)&mask, (void*)&Wf, (void*)&Wi, (void*)&Wo,
                      (void*)&Wc, (void*)&Zx, (void*)&hP, (void*)&xb,
                      (void*)&out };
    hipLaunchCooperativeKernel(reinterpret_cast<void*>(&lstm_rec_fast),
                               dim3(128), dim3(512), kargs, 0, stream);
  } else {
    float* hT = (float*)d_ws;
    const size_t h_bytes = 2 * 64 * 512 * 4;                    // 256 KiB
    unsigned* cnt = (unsigned*)((char*)hT + h_bytes);
    hipMemsetAsync(hT, 0, h_bytes + 4096, stream);
    void* kargs[] = { (void*)&x, (void*)&mask, (void*)&Wf, (void*)&Wi,
                      (void*)&Wo, (void*)&Wc, (void*)&bf, (void*)&bi,
                      (void*)&bo, (void*)&bc, (void*)&hT, (void*)&cnt,
                      (void*)&out };
    hipLaunchCooperativeKernel(reinterpret_cast<void*>(&lstm_rec_inline),
                               dim3(256), dim3(512), kargs, 0, stream);
  }
}

// Round 16
// 3465.886 us; speedup vs baseline: 1.1540x; 1.0003x over previous
//
#include <hip/hip_runtime.h>
#include <math.h>

// Problem constants (fixed by the reference)
#define T_STEPS 512
#define BATCH   64
#define HID     512
#define NROW    2048          // 4*HID rows of concatenated W
#define HHIST   16777216ULL   // T*B*H floats (offset of i_hist in d_out)

typedef __attribute__((ext_vector_type(8))) short short8_t;   // 8 bf16
typedef __attribute__((ext_vector_type(4))) float float4_t;   // MFMA acc / nt
typedef __attribute__((ext_vector_type(4))) unsigned uint4_t; // dwordx4

// ---------------------------------------------------------------------------
// helpers
// ---------------------------------------------------------------------------
__device__ __forceinline__ float sigf(float z) {
  z = fminf(fmaxf(z, -30.f), 30.f);
  return 1.f / (1.f + __expf(-z));
}
__device__ __forceinline__ float tanhf_(float v) {
  v = fminf(fmaxf(v, -15.f), 15.f);
  const float e = __expf(2.f * v);
  return (e - 1.f) / (e + 1.f);
}
__device__ __forceinline__ unsigned short bf16hi(float f) {
  unsigned u = __float_as_uint(f);
  return (unsigned short)((u + 0x7fffu + ((u >> 16) & 1u)) >> 16);  // RNE
}
__device__ __forceinline__ float bf16f(unsigned short h) {
  return __uint_as_float(((unsigned)h) << 16);
}
// pack f as (hi bf16 << 16) | (lo bf16): hi + lo ~ f to ~2^-17 rel.
__device__ __forceinline__ unsigned packh(float f) {
  unsigned short h = bf16hi(f);
  unsigned short l = bf16hi(f - bf16f(h));
  return (((unsigned)h) << 16) | (unsigned)l;
}

// Fast poll of one 64B row (8 tagged u64) via 4x global_load_dwordx4 sc0 —
// bypasses L1, served by this XCD's L2.
__device__ __forceinline__ bool poll_fast(const unsigned long long* hq, unsigned t,
                                          uint4_t& a, uint4_t& b,
                                          uint4_t& c, uint4_t& d) {
  asm volatile(
      "global_load_dwordx4 %0, %4, off sc0\n\t"
      "global_load_dwordx4 %1, %4, off offset:16 sc0\n\t"
      "global_load_dwordx4 %2, %4, off offset:32 sc0\n\t"
      "global_load_dwordx4 %3, %4, off offset:48 sc0\n\t"
      "s_waitcnt vmcnt(0)"
      : "=&v"(a), "=&v"(b), "=&v"(c), "=&v"(d)
      : "v"(hq)
      : "memory");
  return a[1] == t && a[3] == t && b[1] == t && b[3] == t &&
         c[1] == t && c[3] == t && d[1] == t && d[3] == t;
}

// ---------------------------------------------------------------------------
// Kernel A (unchanged): Zx[t][g][r][b8] = b[r] + sum_k Wx[r][k]*x[..]
// Layout [t][8 groups][2048 rows][8 b].
// ---------------------------------------------------------------------------
__global__ __launch_bounds__(256) void xgemm_kernel(
    const float* __restrict__ x,
    const float* __restrict__ Wf, const float* __restrict__ Wi,
    const float* __restrict__ Wo, const float* __restrict__ Wc,
    const float* __restrict__ bf, const float* __restrict__ bi,
    const float* __restrict__ bo, const float* __restrict__ bc,
    float* __restrict__ Zx)
{
  const int rtile = blockIdx.x;   // 0..15
  const int t     = blockIdx.y;   // 0..511
  const int g  = rtile >> 2;
  const int n0 = (rtile & 3) * 128;
  const float* Wg = (g == 0) ? Wf : (g == 1) ? Wi : (g == 2) ? Wo : Wc;
  const float* bg = (g == 0) ? bf : (g == 1) ? bi : (g == 2) ? bo : bc;

  __shared__ float Wt[32][132];   // [k][r] transposed, padded
  __shared__ float Xt[32][68];    // [k][b] transposed, padded

  const int tid = threadIdx.x;
  const int tr  = tid & 31;       // 4 r-rows each
  const int tb  = tid >> 5;       // 8 b-cols each (= batch group tb)

  float acc[4][8];
#pragma unroll
  for (int i = 0; i < 4; ++i)
#pragma unroll
    for (int j = 0; j < 8; ++j) acc[i][j] = 0.f;

  float biasv[4];
#pragma unroll
  for (int i = 0; i < 4; ++i) biasv[i] = bg[n0 + tr * 4 + i];

  const float* xt = x + (size_t)t * (BATCH * 512);

  for (int kc = 0; kc < 512; kc += 32) {
#pragma unroll
    for (int p = 0; p < 4; ++p) {
      const int r  = p * 32 + (tid >> 3);
      const int kk = (tid & 7) * 4;
      float4 v = *(const float4*)&Wg[(size_t)(n0 + r) * 1024 + 512 + kc + kk];
      Wt[kk + 0][r] = v.x; Wt[kk + 1][r] = v.y;
      Wt[kk + 2][r] = v.z; Wt[kk + 3][r] = v.w;
    }
    {
      const int b  = tid >> 2;
      const int kk = (tid & 3) * 8;
      float4 v0 = *(const float4*)&xt[b * 512 + kc + kk];
      float4 v1 = *(const float4*)&xt[b * 512 + kc + kk + 4];
      Xt[kk + 0][b] = v0.x; Xt[kk + 1][b] = v0.y;
      Xt[kk + 2][b] = v0.z; Xt[kk + 3][b] = v0.w;
      Xt[kk + 4][b] = v1.x; Xt[kk + 5][b] = v1.y;
      Xt[kk + 6][b] = v1.z; Xt[kk + 7][b] = v1.w;
    }
    __syncthreads();
#pragma unroll
    for (int kk = 0; kk < 32; ++kk) {
      float4 wv = *(const float4*)&Wt[kk][tr * 4];
      float4 x0 = *(const float4*)&Xt[kk][tb * 8];
      float4 x1 = *(const float4*)&Xt[kk][tb * 8 + 4];
      const float wa[4] = {wv.x, wv.y, wv.z, wv.w};
      const float xa[8] = {x0.x, x0.y, x0.z, x0.w, x1.x, x1.y, x1.z, x1.w};
#pragma unroll
      for (int i = 0; i < 4; ++i)
#pragma unroll
        for (int j = 0; j < 8; ++j)
          acc[i][j] = fmaf(wa[i], xa[j], acc[i][j]);
    }
    __syncthreads();
  }

  const int rg = g * 512 + n0 + tr * 4;
#pragma unroll
  for (int ir = 0; ir < 4; ++ir) {
    const float bv = biasv[ir];
    float4 o0 = make_float4(acc[ir][0] + bv, acc[ir][1] + bv,
                            acc[ir][2] + bv, acc[ir][3] + bv);
    float4 o1 = make_float4(acc[ir][4] + bv, acc[ir][5] + bv,
                            acc[ir][6] + bv, acc[ir][7] + bv);
    // [t][group = tb][row][8 b]
    float* dst = Zx + (((size_t)t * 8 + tb) * NROW + rg + ir) * 8;
    *(float4*)dst       = o0;
    *(float4*)(dst + 4) = o1;
  }
}

// ---------------------------------------------------------------------------
// Kernel B (fast): r14 structure (XCD-discovered groups, MFMA, in-wave
// epilogue, adaptive L2/MALL polling, nt Zx prefetch), with STORE-ACKS
// REMOVED FROM THE SERIAL CHAIN:
//  - out history is staged in LDS (obuf[t&7][b][u], 16KB) and flushed every
//    8 steps as coalesced 128B-run float4 nt stores. The per-step epilogue
//    issues NO global out stores, so the next poll's vmcnt(0) no longer
//    drains ~1us of fragmented HBM write-acks (stores count in vmcnt on
//    CDNA). RMW write-amp also disappears (128B contiguous runs).
//  - hP publish (plain + sc1) is issued FIRST in the epilogue.
// Correctness identical to r12/r14: epoch tags are ground truth; dual
// publish; adaptive permanent fallback to agent/MALL polling.
// ---------------------------------------------------------------------------
__global__ __launch_bounds__(512, 2) void lstm_rec_fast(
    const float* __restrict__ mask,
    const float* __restrict__ Wf, const float* __restrict__ Wi,
    const float* __restrict__ Wo, const float* __restrict__ Wc,
    const float* __restrict__ Zx,
    unsigned long long* __restrict__ hP,   // [2][8 g][8 b][512 k] tagged
    unsigned* __restrict__ xb,             // [0..7] cnt, [15] barrier
    float* __restrict__ out)
{
  __shared__ __align__(16) short hip_[2][8 * 512];  // hi planes [buf][b][k]
  __shared__ __align__(16) short lop_[2][8 * 512];  // lo planes
  __shared__ __align__(16) float obuf_h[8 * 8 * 32]; // [t&7][b][u_l] 8KB
  __shared__ __align__(16) float obuf_i[8 * 8 * 32]; // [t&7][b][u_l] 8KB
  __shared__ unsigned s_role;

  const int tid  = threadIdx.x;

  // ---- phase 0: XCD discovery + role assignment (once) ----
  if (tid == 0) {
    unsigned xcd;
    asm volatile("s_getreg_b32 %0, hwreg(20, 0, 32)" : "=s"(xcd));
    xcd &= 7u;
    const unsigned slot = __hip_atomic_fetch_add(&xb[xcd], 1u, __ATOMIC_RELAXED,
                                                 __HIP_MEMORY_SCOPE_AGENT);
    __builtin_amdgcn_fence(__ATOMIC_RELEASE, "agent");
    __hip_atomic_fetch_add(&xb[15], 1u, __ATOMIC_RELAXED,
                           __HIP_MEMORY_SCOPE_AGENT);
    const unsigned nwg = gridDim.x;
    while (__hip_atomic_load(&xb[15], __ATOMIC_RELAXED,
                             __HIP_MEMORY_SCOPE_AGENT) < nwg)
      __builtin_amdgcn_s_sleep(2);
    __builtin_amdgcn_fence(__ATOMIC_ACQUIRE, "agent");
    unsigned pfx = 0;
    for (unsigned xx = 0; xx < xcd; ++xx)
      pfx += __hip_atomic_load(&xb[xx], __ATOMIC_RELAXED,
                               __HIP_MEMORY_SCOPE_AGENT);
    s_role = pfx + slot;
  }
  __syncthreads();
  const unsigned role = s_role;
  const int g  = (int)(role >> 4);          // batch group (XCD-grouped)
  const int n0 = (int)(role & 15u) * 32;    // first unit of this wg

  const int wv   = tid >> 6;          // wave 0..7
  const int lane = tid & 63;
  const int kq   = lane >> 4;         // k-block / D unit-quadrant
  const int l15  = lane & 15;

  // ---- A fragments: row m = l15 = u_local*4 + gate; k = it*32 + kq*8 + j
  const int gateA = l15 & 3;
  const int unitA = n0 + wv * 4 + (l15 >> 2);
  const float* WmA =
      (gateA == 0) ? Wf : (gateA == 1) ? Wi : (gateA == 2) ? Wo : Wc;
  const float* WrowA = WmA + (size_t)unitA * 1024;   // h-part cols 0..511
  short8_t Ahi[16], Alo[16];
#pragma unroll
  for (int it = 0; it < 16; ++it) {
    const int base = it * 32 + kq * 8;
#pragma unroll
    for (int j = 0; j < 8; ++j) {
      const float f = WrowA[base + j];
      const unsigned short h = bf16hi(f);
      Ahi[it][j] = (short)h;
      Alo[it][j] = (short)bf16hi(f - bf16f(h));
    }
  }

  // epilogue identity: lane holds gates of (unitD, bD); active if l15 < 8
  const int unitD = n0 + wv * 4 + kq;
  const int uL    = wv * 4 + kq;      // unit-local 0..31
  const int bD    = l15;
  const bool act  = (l15 < 8);
  float c_r = 0.f, h_r = 0.f;

  // staging identity: thread owns (b_s, kr..kr+7) -> exactly ONE producer wg
  const int b_s = tid >> 6;            // 0..7
  const int kr  = (tid & 63) * 8;      // k start
  const int bcol = l15 & 7;            // dot-side B row (lanes 8-15 duplicate)

  // out-flush identity (every 8 steps): thread -> (t_l, b, nl4)
  const int f_tl  = tid >> 6;          // 0..7
  const int f_b   = (tid >> 3) & 7;    // 0..7
  const int f_nl4 = (tid & 7) * 4;     // 0,4,..,28

  bool fastok = true;                  // per-(consumer,producer) adaptive

  // ---- prologue: Zx/mask for t=0 (nt loads; in flight during first poll)
  float zxc[4] = {0.f, 0.f, 0.f, 0.f};
  float mvc = 0.f;
  if (act) {
    mvc = __builtin_nontemporal_load(&mask[g * 8 + bD]);
#pragma unroll
    for (int r = 0; r < 4; ++r)
      zxc[r] = __builtin_nontemporal_load(
          &Zx[(((size_t)0 * 8 + g) * NROW + r * 512 + unitD) * 8 + bD]);
  }

  for (int t = 0; t < T_STEPS; ++t) {
    // ---- poll own 8 tagged pairs: adaptive L2-fast / MALL-robust
    {
      const unsigned long long* hq =
          hP + (((size_t)(t & 1) * 8 + g) * 8 + b_s) * 512 + kr;
      unsigned p8[8];
      bool got = false;
      if (fastok) {
        uint4_t a, b, c, d;
        for (int it2 = 0; it2 < 64 && !got; ++it2)
          got = poll_fast(hq, (unsigned)t, a, b, c, d);
        if (got) {
          p8[0] = a[0]; p8[1] = a[2]; p8[2] = b[0]; p8[3] = b[2];
          p8[4] = c[0]; p8[5] = c[2]; p8[6] = d[0]; p8[7] = d[2];
        } else {
          fastok = false;   // producer not L2-visible: use MALL from now on
        }
      }
      if (!got) {
        unsigned long long q[8];
        while (true) {
#pragma unroll
          for (int j = 0; j < 8; ++j)
            q[j] = __hip_atomic_load(hq + j, __ATOMIC_RELAXED,
                                     __HIP_MEMORY_SCOPE_AGENT);
          bool ok = true;
#pragma unroll
          for (int j = 0; j < 8; ++j)
            ok &= ((unsigned)(q[j] >> 32) == (unsigned)t);
          if (ok) break;
          __builtin_amdgcn_s_sleep(1);
        }
#pragma unroll
        for (int j = 0; j < 8; ++j) p8[j] = (unsigned)q[j];
      }
      short8_t H, L;
#pragma unroll
      for (int j = 0; j < 8; ++j) {
        H[j] = (short)(p8[j] >> 16);
        L[j] = (short)(p8[j] & 0xffffu);
      }
      const int sOff = b_s * 1024 + ((kr * 2) ^ ((b_s & 7) << 4));
      *(short8_t*)((char*)hip_[t & 1] + sOff) = H;
      *(short8_t*)((char*)lop_[t & 1] + sOff) = L;
    }

    // ---- prefetch t+1's Zx/mask (nt; consumed at the NEXT epilogue, so
    // the HBM latency hides under a full step)
    float zxn[4] = {0.f, 0.f, 0.f, 0.f};
    float mvn = 0.f;
    if (act && t + 1 < T_STEPS) {
      mvn = __builtin_nontemporal_load(&mask[(t + 1) * 64 + g * 8 + bD]);
#pragma unroll
      for (int r = 0; r < 4; ++r)
        zxn[r] = __builtin_nontemporal_load(
            &Zx[(((size_t)(t + 1) * 8 + g) * NROW + r * 512 + unitD) * 8 + bD]);
    }

    __syncthreads();   // planes ready

    // ---- MFMA: 16 rows x 16 cols x K=512, 3-pass split-bf16
    float4_t c0 = {0.f, 0.f, 0.f, 0.f};
    float4_t c1 = {0.f, 0.f, 0.f, 0.f};
    float4_t c2 = {0.f, 0.f, 0.f, 0.f};
    {
      const char* hib = (const char*)hip_[t & 1] + bcol * 1024;
      const char* lob = (const char*)lop_[t & 1] + bcol * 1024;
      const int xr = bcol << 4;
#pragma unroll
      for (int it = 0; it < 16; ++it) {
        const int o = it * 64 + kq * 16;
        const short8_t bh = *(const short8_t*)(hib + (o ^ xr));
        const short8_t bl = *(const short8_t*)(lob + (o ^ xr));
        c0 = __builtin_amdgcn_mfma_f32_16x16x32_bf16(Ahi[it], bh, c0, 0, 0, 0);
        c1 = __builtin_amdgcn_mfma_f32_16x16x32_bf16(Ahi[it], bl, c1, 0, 0, 0);
        c2 = __builtin_amdgcn_mfma_f32_16x16x32_bf16(Alo[it], bh, c2, 0, 0, 0);
      }
    }

    // ---- per-lane epilogue: r = gate (rows kq*4+r), no cross-lane traffic
    if (act) {
      float z[4];
#pragma unroll
      for (int r = 0; r < 4; ++r) z[r] = c0[r] + c1[r] + c2[r] + zxc[r];
      const float f  = sigf(z[0]);
      const float ig = sigf(z[1]);
      const float o  = sigf(z[2]);
      const float ct = tanhf_(z[3]);
      float cn = f * c_r + ig * ct;
      cn = mvc * cn + (1.f - mvc) * c_r;
      c_r = cn;
      float hn = o * tanhf_(cn);
      hn = mvc * hn + (1.f - mvc) * h_r;
      h_r = hn;
      // publish FIRST (acks overlap the LDS writes below):
      // plain -> local XCD L2 (fast path); sc1 -> MALL (robust path)
      const size_t hidx =
          (((size_t)((t + 1) & 1) * 8 + g) * 8 + bD) * 512 + unitD;
      const unsigned long long pk =
          (((unsigned long long)(unsigned)(t + 1)) << 32) |
          (unsigned long long)packh(hn);
      *(volatile unsigned long long*)(hP + hidx) = pk;
      __hip_atomic_store(hP + hidx, pk, __ATOMIC_RELAXED,
                         __HIP_MEMORY_SCOPE_AGENT);
      // history values -> LDS (NO global stores on the per-step path)
      obuf_h[((t & 7) * 8 + bD) * 32 + uL] = hn;
      obuf_i[((t & 7) * 8 + bD) * 32 + uL] = ig;
    }

    // ---- every 8 steps: coalesced nt flush of the history buffer
    if ((t & 7) == 7) {
      __syncthreads();   // obuf writes visible to all waves
      const int T0 = t - 7;
      const float4_t hv = *(const float4_t*)&obuf_h[(f_tl * 8 + f_b) * 32 + f_nl4];
      const float4_t iv = *(const float4_t*)&obuf_i[(f_tl * 8 + f_b) * 32 + f_nl4];
      const size_t ob =
          ((size_t)(T0 + f_tl) * 64 + g * 8 + f_b) * 512 + n0 + f_nl4;
      __builtin_nontemporal_store(hv, (float4_t*)&out[ob]);
      __builtin_nontemporal_store(iv, (float4_t*)&out[HHIST + ob]);
      // no barrier needed after: obuf[t&7] slots are only rewritten after
      // the NEXT planes-barrier, which every wave must pass first.
    }

    // rotate Zx double-buffer
#pragma unroll
    for (int r = 0; r < 4; ++r) zxc[r] = zxn[r];
    mvc = mvn;
  }
}

// ---------------------------------------------------------------------------
// Fallback (ws too small): round-3 inline-x cooperative version, verbatim.
// ---------------------------------------------------------------------------
__device__ __forceinline__ void grid_barrier(unsigned* cnt, int w, int tid, int round) {
  __syncthreads();
  if (tid == 0) {
    __builtin_amdgcn_fence(__ATOMIC_RELEASE, "agent");
    unsigned* gc = cnt + 16 + ((w >> 4) << 5);
    unsigned prev = __hip_atomic_fetch_add(gc, 1u, __ATOMIC_RELAXED,
                                           __HIP_MEMORY_SCOPE_AGENT);
    if ((prev & 15u) == 15u)
      __hip_atomic_fetch_add(cnt, 1u, __ATOMIC_RELAXED,
                             __HIP_MEMORY_SCOPE_AGENT);
    const unsigned target = (unsigned)(round + 1) * 16u;
    while (__hip_atomic_load(cnt, __ATOMIC_RELAXED,
                             __HIP_MEMORY_SCOPE_AGENT) < target)
      __builtin_amdgcn_s_sleep(2);
    __builtin_amdgcn_fence(__ATOMIC_ACQUIRE, "agent");
  }
  __syncthreads();
}

__global__ __launch_bounds__(512) void lstm_rec_inline(
    const float* __restrict__ x,  const float* __restrict__ mask,
    const float* __restrict__ Wf, const float* __restrict__ Wi,
    const float* __restrict__ Wo, const float* __restrict__ Wc,
    const float* __restrict__ bf, const float* __restrict__ bi,
    const float* __restrict__ bo, const float* __restrict__ bc,
    float* __restrict__ hT, unsigned* __restrict__ cnt,
    float* __restrict__ out)
{
  constexpr int WC = 1024;
  __shared__ float Wlds[8 * WC];
  __shared__ float zpart[8 * 8 * 64];

  const int tid = threadIdx.x;
  const int w   = blockIdx.x;
  const int kq  = tid >> 6;
  const int b   = tid & 63;
  const int n0  = ((w & 7) << 6) + ((w >> 3) << 1);

#pragma unroll
  for (int i = 0; i < WC / 256; ++i) {
    const int idx4 = tid + (i << 9);
    const int rr   = idx4 / (WC / 4);
    const int col  = (idx4 % (WC / 4)) * 4;
    const int g = rr >> 1, u = rr & 1;
    const float* Wrow =
        ((g == 0) ? Wf : (g == 1) ? Wi : (g == 2) ? Wo : Wc) +
        (size_t)(n0 + u) * 1024;
    *(float4*)&Wlds[rr * WC + col] = *(const float4*)&Wrow[col];
  }

  float biasv[4] = {0.f, 0.f, 0.f, 0.f};
  float c_r = 0.f, h_r = 0.f;
  if (tid < 128) {
    const int u = tid >> 6;
    biasv[0] = bf[n0 + u]; biasv[1] = bi[n0 + u];
    biasv[2] = bo[n0 + u]; biasv[3] = bc[n0 + u];
  }
  __syncthreads();

  for (int t = 0; t < T_STEPS; ++t) {
    float zpre[4] = {0.f, 0.f, 0.f, 0.f};
    float mval = 0.f;
    if (tid < 128) {
      const int bb = tid & 63;
      mval = mask[t * 64 + bb];
#pragma unroll
      for (int g = 0; g < 4; ++g) zpre[g] = biasv[g];
    }

    float acc[8];
#pragma unroll
    for (int rr = 0; rr < 8; ++rr) acc[rr] = 0.f;

    {
      const float* hcur = hT + ((t & 1) << 15);
      const int k0 = kq << 6;
#pragma unroll
      for (int k4 = 0; k4 < 16; ++k4) {
        const int k = k0 + (k4 << 2);
        const float h0 = hcur[(k + 0) * 64 + b];
        const float h1 = hcur[(k + 1) * 64 + b];
        const float h2 = hcur[(k + 2) * 64 + b];
        const float h3 = hcur[(k + 3) * 64 + b];
#pragma unroll
        for (int rr = 0; rr < 8; ++rr) {
          float4 wv = *(const float4*)&Wlds[rr * WC + k];
          acc[rr] = fmaf(h0, wv.x, acc[rr]);
          acc[rr] = fmaf(h1, wv.y, acc[rr]);
          acc[rr] = fmaf(h2, wv.z, acc[rr]);
          acc[rr] = fmaf(h3, wv.w, acc[rr]);
        }
      }
    }
    {
      const float* xt = x + (size_t)t * (64 * 512) + b * 512;
      const int k0 = kq << 6;
#pragma unroll
      for (int k4 = 0; k4 < 16; ++k4) {
        const int k = k0 + (k4 << 2);
        float4 xv = *(const float4*)&xt[k];
#pragma unroll
        for (int rr = 0; rr < 8; ++rr) {
          float4 wv = *(const float4*)&Wlds[rr * WC + 512 + k];
          acc[rr] = fmaf(xv.x, wv.x, acc[rr]);
          acc[rr] = fmaf(xv.y, wv.y, acc[rr]);
          acc[rr] = fmaf(xv.z, wv.z, acc[rr]);
          acc[rr] = fmaf(xv.w, wv.w, acc[rr]);
        }
      }
    }

#pragma unroll
    for (int rr = 0; rr < 8; ++rr)
      zpart[((kq << 3) + rr) * 64 + b] = acc[rr];
    __syncthreads();

    if (tid < 128) {
      const int u = tid >> 6, bb = tid & 63;
      float z[4];
#pragma unroll
      for (int g = 0; g < 4; ++g) {
        const int rr = g * 2 + u;
        float s = zpre[g];
#pragma unroll
        for (int q = 0; q < 8; ++q) s += zpart[((q << 3) + rr) * 64 + bb];
        z[g] = s;
      }
      const float f  = sigf(z[0]);
      const float ig = sigf(z[1]);
      const float o  = sigf(z[2]);
      const float ct = tanhf_(z[3]);
      float cn = f * c_r + ig * ct;
      cn = mval * cn + (1.f - mval) * c_r;
      c_r = cn;
      float hn = o * tanhf_(cn);
      hn = mval * hn + (1.f - mval) * h_r;
      h_r = hn;
      const int n = n0 + u;
      hT[(((t + 1) & 1) << 15) + n * 64 + bb] = hn;
      out[((size_t)t * 64 + bb) * 512 + n]         = hn;
      out[HHIST + ((size_t)t * 64 + bb) * 512 + n] = ig;
    }

    if (t != T_STEPS - 1) grid_barrier(cnt, w, tid, t);
  }
}

// ---------------------------------------------------------------------------
// launch
// ---------------------------------------------------------------------------
extern "C" void kernel_launch(void* const* d_in, const int* in_sizes, int n_in,
                              void* d_out, int out_size, void* d_ws, size_t ws_size,
                              hipStream_t stream) {
  (void)in_sizes; (void)n_in; (void)out_size;
  // setup_inputs order: x, mask, Wf, bf, Wi, bi, Wc, bc, Wo, bo
  const float* x    = (const float*)d_in[0];
  const float* mask = (const float*)d_in[1];
  const float* Wf   = (const float*)d_in[2];
  const float* bf   = (const float*)d_in[3];
  const float* Wi   = (const float*)d_in[4];
  const float* bi   = (const float*)d_in[5];
  const float* Wc   = (const float*)d_in[6];
  const float* bc   = (const float*)d_in[7];
  const float* Wo   = (const float*)d_in[8];
  const float* bo   = (const float*)d_in[9];
  float* out = (float*)d_out;

  const size_t zx_bytes = (size_t)T_STEPS * NROW * 64 * 4;      // 256 MiB
  const size_t hp_bytes = (size_t)2 * 8 * 8 * 512 * 8;          // 512 KiB
  const bool fast = ws_size >= zx_bytes + hp_bytes + 4096;

  if (fast) {
    float* Zx = (float*)d_ws;
    unsigned long long* hP = (unsigned long long*)((char*)d_ws + zx_bytes);
    unsigned* xb = (unsigned*)((char*)hP + hp_bytes);
    // zero tagged buffer (epoch 0 = t=0 initial h) + discovery counters
    hipMemsetAsync(hP, 0, hp_bytes + 4096, stream);
    hipLaunchKernelGGL(xgemm_kernel, dim3(16, 512), dim3(256), 0, stream,
                       x, Wf, Wi, Wo, Wc, bf, bi, bo, bc, Zx);
    void* kargs[] = { (void*)&mask, (void*)&Wf, (void*)&Wi, (void*)&Wo,
                      (void*)&Wc, (void*)&Zx, (void*)&hP, (void*)&xb,
                      (void*)&out };
    hipLaunchCooperativeKernel(reinterpret_cast<void*>(&lstm_rec_fast),
                               dim3(128), dim3(512), kargs, 0, stream);
  } else {
    float* hT = (float*)d_ws;
    const size_t h_bytes = 2 * 64 * 512 * 4;                    // 256 KiB
    unsigned* cnt = (unsigned*)((char*)hT + h_bytes);
    hipMemsetAsync(hT, 0, h_bytes + 4096, stream);
    void* kargs[] = { (void*)&x, (void*)&mask, (void*)&Wf, (void*)&Wi,
                      (void*)&Wo, (void*)&Wc, (void*)&bf, (void*)&bi,
                      (void*)&bo, (void*)&bc, (void*)&hT, (void*)&cnt,
                      (void*)&out };
    hipLaunchCooperativeKernel(reinterpret_cast<void*>(&lstm_rec_inline),
                               dim3(256), dim3(512), kargs, 0, stream);
  }
}